// Round 1
// baseline (287.918 us; speedup 1.0000x reference)
//
#include <hip/hip_runtime.h>

// SimpleEncoder: LSTM(B=4096, S=512, I=3, H=16) + Linear(16->5) + clip(+-10)
//
// Strategy: 16 lanes per batch element; lane j owns hidden unit j and computes
// gate rows {j, j+16, j+32, j+48}. h broadcast within 16-lane groups via
// ds_swizzle. All weights in registers (log2e pre-folded for exp2-based
// activations). Output projection folded into the gate FMA loop (1-step delay).

#define TS 512
#define LOG2E 1.44269504088896340736f

#define SWZ(K) hb[K] = __int_as_float(__builtin_amdgcn_ds_swizzle(hvi, ((K) << 5) | 0x10))
#define SWZ_ALL() \
  SWZ(0); SWZ(1); SWZ(2); SWZ(3); SWZ(4); SWZ(5); SWZ(6); SWZ(7); \
  SWZ(8); SWZ(9); SWZ(10); SWZ(11); SWZ(12); SWZ(13); SWZ(14); SWZ(15)

__global__ __launch_bounds__(256, 1)
void lstm_enc_kernel(const float* __restrict__ x,
                     const float* __restrict__ W_ih,
                     const float* __restrict__ W_hh,
                     const float* __restrict__ b_ih,
                     const float* __restrict__ b_hh,
                     const float* __restrict__ W_lin,
                     const float* __restrict__ b_lin,
                     float* __restrict__ out) {
  const int tid = threadIdx.x;
  const int j = tid & 15;                       // hidden unit owned by this lane
  const int batch = blockIdx.x * 16 + (tid >> 4);
  const int jo = (j < 5) ? j : 0;               // clamped row for W_lin loads

  // ---- preload all weights into registers (log2e folded for exp2 activations)
  float whi[16], whf[16], whg[16], who[16], wl[16];
#pragma unroll
  for (int k = 0; k < 16; ++k) {
    whi[k] = W_hh[(j     ) * 16 + k] * LOG2E;
    whf[k] = W_hh[(j + 16) * 16 + k] * LOG2E;
    whg[k] = W_hh[(j + 32) * 16 + k] * (2.0f * LOG2E);
    who[k] = W_hh[(j + 48) * 16 + k] * LOG2E;
    wl[k]  = W_lin[jo * 16 + k];
  }
  float wii[3], wif[3], wig[3], wio[3];
#pragma unroll
  for (int i = 0; i < 3; ++i) {
    wii[i] = W_ih[(j     ) * 3 + i] * LOG2E;
    wif[i] = W_ih[(j + 16) * 3 + i] * LOG2E;
    wig[i] = W_ih[(j + 32) * 3 + i] * (2.0f * LOG2E);
    wio[i] = W_ih[(j + 48) * 3 + i] * LOG2E;
  }
  const float bi = (b_ih[j     ] + b_hh[j     ]) * LOG2E;
  const float bf = (b_ih[j + 16] + b_hh[j + 16]) * LOG2E;
  const float bg = (b_ih[j + 32] + b_hh[j + 32]) * (2.0f * LOG2E);
  const float bo = (b_ih[j + 48] + b_hh[j + 48]) * LOG2E;
  const float bl = b_lin[jo];

  const float* __restrict__ xb = x + (size_t)batch * (TS * 3);
  float* __restrict__ ob = out + (size_t)batch * (TS * 5) + j;

  float h = 0.0f, c = 0.0f;
  float x0 = xb[0], x1 = xb[1], x2 = xb[2];

  for (int t = 0; t < TS; ++t) {
    // prefetch next timestep's input ((t+1)&511 wraps in-bounds at the end)
    const int tn = (t + 1) & (TS - 1);
    const float nx0 = xb[tn * 3 + 0];
    const float nx1 = xb[tn * 3 + 1];
    const float nx2 = xb[tn * 3 + 2];

    // broadcast h_{t-1} across the 16-lane group
    float hb[16];
    const int hvi = __float_as_int(h);
    SWZ_ALL();

    // gate pre-activations (pre-scaled by log2e / 2log2e) + output projection
    float ai = bi, af = bf, ag = bg, ao = bo, oa = bl;
    ai = fmaf(x0, wii[0], ai); ai = fmaf(x1, wii[1], ai); ai = fmaf(x2, wii[2], ai);
    af = fmaf(x0, wif[0], af); af = fmaf(x1, wif[1], af); af = fmaf(x2, wif[2], af);
    ag = fmaf(x0, wig[0], ag); ag = fmaf(x1, wig[1], ag); ag = fmaf(x2, wig[2], ag);
    ao = fmaf(x0, wio[0], ao); ao = fmaf(x1, wio[1], ao); ao = fmaf(x2, wio[2], ao);
#pragma unroll
    for (int k = 0; k < 16; ++k) {
      ai = fmaf(hb[k], whi[k], ai);
      af = fmaf(hb[k], whf[k], af);
      ag = fmaf(hb[k], whg[k], ag);
      ao = fmaf(hb[k], who[k], ao);
      oa = fmaf(hb[k], wl[k], oa);   // W_lin . h_{t-1}  -> out[t-1]
    }

    // store previous timestep's output (oa is based on h_{t-1})
    if (t > 0 && j < 5) {
      ob[(t - 1) * 5] = fminf(fmaxf(oa, -10.0f), 10.0f);
    }

    // activations: sigmoid(z) = rcp(1 + exp2(-z*log2e)); tanh via exp2
    const float ig = __builtin_amdgcn_rcpf(1.0f + __builtin_amdgcn_exp2f(-ai));
    const float fg = __builtin_amdgcn_rcpf(1.0f + __builtin_amdgcn_exp2f(-af));
    const float gg = fmaf(-2.0f, __builtin_amdgcn_rcpf(1.0f + __builtin_amdgcn_exp2f(ag)), 1.0f);
    const float og = __builtin_amdgcn_rcpf(1.0f + __builtin_amdgcn_exp2f(-ao));

    c = fmaf(fg, c, ig * gg);
    const float tc = fmaf(-2.0f,
        __builtin_amdgcn_rcpf(1.0f + __builtin_amdgcn_exp2f((2.0f * LOG2E) * c)), 1.0f);
    h = og * tc;

    x0 = nx0; x1 = nx1; x2 = nx2;
  }

  // final timestep's output (uses h_{S-1})
  {
    float hb[16];
    const int hvi = __float_as_int(h);
    SWZ_ALL();
    float oa = bl;
#pragma unroll
    for (int k = 0; k < 16; ++k) oa = fmaf(hb[k], wl[k], oa);
    if (j < 5) {
      ob[(TS - 1) * 5] = fminf(fmaxf(oa, -10.0f), 10.0f);
    }
  }
}

extern "C" void kernel_launch(void* const* d_in, const int* in_sizes, int n_in,
                              void* d_out, int out_size, void* d_ws, size_t ws_size,
                              hipStream_t stream) {
  const float* x     = (const float*)d_in[0];
  const float* W_ih  = (const float*)d_in[1];
  const float* W_hh  = (const float*)d_in[2];
  const float* b_ih  = (const float*)d_in[3];
  const float* b_hh  = (const float*)d_in[4];
  const float* W_lin = (const float*)d_in[5];
  const float* b_lin = (const float*)d_in[6];
  float* out = (float*)d_out;

  const int B = in_sizes[0] / (TS * 3);   // 4096
  const int grid = B / 16;                // 16 batch elements per 256-thread block
  lstm_enc_kernel<<<grid, 256, 0, stream>>>(x, W_ih, W_hh, b_ih, b_hh, W_lin, b_lin, out);
}

// Round 2
// 236.497 us; speedup vs baseline: 1.2174x; 1.2174x over previous
//
#include <hip/hip_runtime.h>

// SimpleEncoder: LSTM(B=4096, S=512, I=3, H=16) + Linear(16->5) + clip(+-10)
//
// R2: 16 lanes per batch element; lane j owns hidden unit j (gate rows
// j, j+16, j+32, j+48). h_{t-1} broadcast within each 16-lane row via DPP
// row_newbcast (VALU pipe, ~4 cyc) instead of ds_swizzle (~120 cyc LDS pipe).
// Gate pairs (i,f) and (g,o) accumulate as float2 -> v_pk_fma_f32, halving
// the FMA issue count. Weights in registers, log2e pre-folded so activations
// use native v_exp_f32 (exp2) + v_rcp_f32.

#define TS 512
#define LOG2E 1.44269504088896340736f

typedef float f32x2 __attribute__((ext_vector_type(2)));

// DPP row_newbcast:K — broadcast lane K of each 16-lane row to the whole row.
#define BCAST(K) hbr[K] = __int_as_float( \
    __builtin_amdgcn_update_dpp(0, hvi, 0x150 + (K), 0xf, 0xf, true))
#define BCAST_ALL() \
  BCAST(0); BCAST(1); BCAST(2); BCAST(3); BCAST(4); BCAST(5); BCAST(6); BCAST(7); \
  BCAST(8); BCAST(9); BCAST(10); BCAST(11); BCAST(12); BCAST(13); BCAST(14); BCAST(15)

__global__ __launch_bounds__(256, 1)
void lstm_enc_kernel(const float* __restrict__ x,
                     const float* __restrict__ W_ih,
                     const float* __restrict__ W_hh,
                     const float* __restrict__ b_ih,
                     const float* __restrict__ b_hh,
                     const float* __restrict__ W_lin,
                     const float* __restrict__ b_lin,
                     float* __restrict__ out) {
  const int tid = threadIdx.x;
  const int j = tid & 15;                       // hidden unit owned by this lane
  const int batch = blockIdx.x * 16 + (tid >> 4);
  const int jo = (j < 5) ? j : 0;               // clamped row for W_lin loads

  // ---- preload weights into registers, packed by gate-pair, log2e folded
  f32x2 wif[16], wgo[16];                       // {W_i, W_f}[k], {W_g, W_o}[k]
  float wl[16];
#pragma unroll
  for (int k = 0; k < 16; ++k) {
    wif[k] = f32x2{W_hh[(j     ) * 16 + k] * LOG2E,
                   W_hh[(j + 16) * 16 + k] * LOG2E};
    wgo[k] = f32x2{W_hh[(j + 32) * 16 + k] * (2.0f * LOG2E),
                   W_hh[(j + 48) * 16 + k] * LOG2E};
    wl[k]  = W_lin[jo * 16 + k];
  }
  f32x2 xif[3], xgo[3];
#pragma unroll
  for (int i = 0; i < 3; ++i) {
    xif[i] = f32x2{W_ih[(j     ) * 3 + i] * LOG2E,
                   W_ih[(j + 16) * 3 + i] * LOG2E};
    xgo[i] = f32x2{W_ih[(j + 32) * 3 + i] * (2.0f * LOG2E),
                   W_ih[(j + 48) * 3 + i] * LOG2E};
  }
  const f32x2 bif = f32x2{(b_ih[j     ] + b_hh[j     ]) * LOG2E,
                          (b_ih[j + 16] + b_hh[j + 16]) * LOG2E};
  const f32x2 bgo = f32x2{(b_ih[j + 32] + b_hh[j + 32]) * (2.0f * LOG2E),
                          (b_ih[j + 48] + b_hh[j + 48]) * LOG2E};
  const float bl = b_lin[jo];

  const float* __restrict__ xb = x + (size_t)batch * (TS * 3);
  float* __restrict__ ob = out + (size_t)batch * (TS * 5) + j;

  float h = 0.0f, c = 0.0f;
  float x0 = xb[0], x1 = xb[1], x2 = xb[2];

  for (int t = 0; t < TS; ++t) {
    // prefetch next timestep's input ((t+1)&511 wraps in-bounds at the end)
    const int tn = (t + 1) & (TS - 1);
    const float nx0 = xb[tn * 3 + 0];
    const float nx1 = xb[tn * 3 + 1];
    const float nx2 = xb[tn * 3 + 2];

    // broadcast h_{t-1} across the 16-lane row (DPP, VALU pipe)
    float hbr[16];
    const int hvi = __float_as_int(h);
    BCAST_ALL();

    // gate pre-activations (pre-scaled by log2e / 2log2e), packed pairs,
    // + output projection W_lin . h_{t-1} (scalar chain)
    f32x2 aif = bif, ago = bgo;
    float oa = bl;
    aif = f32x2{x0, x0} * xif[0] + aif;
    aif = f32x2{x1, x1} * xif[1] + aif;
    aif = f32x2{x2, x2} * xif[2] + aif;
    ago = f32x2{x0, x0} * xgo[0] + ago;
    ago = f32x2{x1, x1} * xgo[1] + ago;
    ago = f32x2{x2, x2} * xgo[2] + ago;
#pragma unroll
    for (int k = 0; k < 16; ++k) {
      const float hk = hbr[k];
      const f32x2 h2 = f32x2{hk, hk};
      aif = h2 * wif[k] + aif;
      ago = h2 * wgo[k] + ago;
      oa = fmaf(hk, wl[k], oa);
    }

    // store previous timestep's output (oa is based on h_{t-1})
    if (t > 0 && j < 5) {
      ob[(t - 1) * 5] = fminf(fmaxf(oa, -10.0f), 10.0f);
    }

    // activations: sigmoid(z) = rcp(1 + exp2(-z*log2e)); tanh via exp2
    const float ig = __builtin_amdgcn_rcpf(1.0f + __builtin_amdgcn_exp2f(-aif.x));
    const float fg = __builtin_amdgcn_rcpf(1.0f + __builtin_amdgcn_exp2f(-aif.y));
    const float gg = fmaf(-2.0f, __builtin_amdgcn_rcpf(1.0f + __builtin_amdgcn_exp2f(ago.x)), 1.0f);
    const float og = __builtin_amdgcn_rcpf(1.0f + __builtin_amdgcn_exp2f(-ago.y));

    c = fmaf(fg, c, ig * gg);
    const float tc = fmaf(-2.0f,
        __builtin_amdgcn_rcpf(1.0f + __builtin_amdgcn_exp2f((2.0f * LOG2E) * c)), 1.0f);
    h = og * tc;

    x0 = nx0; x1 = nx1; x2 = nx2;
  }

  // final timestep's output (uses h_{S-1})
  {
    float hbr[16];
    const int hvi = __float_as_int(h);
    BCAST_ALL();
    float oa = bl;
#pragma unroll
    for (int k = 0; k < 16; ++k) oa = fmaf(hbr[k], wl[k], oa);
    if (j < 5) {
      ob[(TS - 1) * 5] = fminf(fmaxf(oa, -10.0f), 10.0f);
    }
  }
}

extern "C" void kernel_launch(void* const* d_in, const int* in_sizes, int n_in,
                              void* d_out, int out_size, void* d_ws, size_t ws_size,
                              hipStream_t stream) {
  const float* x     = (const float*)d_in[0];
  const float* W_ih  = (const float*)d_in[1];
  const float* W_hh  = (const float*)d_in[2];
  const float* b_ih  = (const float*)d_in[3];
  const float* b_hh  = (const float*)d_in[4];
  const float* W_lin = (const float*)d_in[5];
  const float* b_lin = (const float*)d_in[6];
  float* out = (float*)d_out;

  const int B = in_sizes[0] / (TS * 3);   // 4096
  const int grid = B / 16;                // 16 batch elements per 256-thread block
  lstm_enc_kernel<<<grid, 256, 0, stream>>>(x, W_ih, W_hh, b_ih, b_hh, W_lin, b_lin, out);
}